// Round 8
// baseline (685.024 us; speedup 1.0000x reference)
//
#include <hip/hip_runtime.h>
#include <math.h>

#define N_PTS 131072
#define HID   256

typedef __attribute__((ext_vector_type(8)))  _Float16 f16x8;
typedef __attribute__((ext_vector_type(4)))  float    f32x4;
typedef __attribute__((ext_vector_type(16))) float    f32x16;
typedef unsigned int u32;
typedef __attribute__((address_space(1))) const u32 gu32;
typedef __attribute__((address_space(3))) u32       lu32;

// LDS map (dynamic, 80 KiB): act[128][256] f16 (64KB) | W double-buffer (2 x 8KB)
// 80KB/block -> 2 blocks/CU co-resident (the point of this round).
#define LDS_HI  0
#define LDS_W   65536
#define LDS_SZ  81920

// act plane: [row][k] f16, 16B-slot XOR on (row&7)
__device__ __forceinline__ int act_off(int row, int kbyte) {
    return row * 512 + (kbyte ^ ((row & 7) << 4));
}
// h = tanh(z), f1 = 1-h^2. Saturation-safe without clamp: s=inf -> h=1, f1=0.
__device__ __forceinline__ void tanh_f1(float z, float& h, float& f1) {
    float s = __expf(2.0f * z);
    float r = __builtin_amdgcn_rcpf(s + 1.0f);
    h  = fmaf(-2.0f, r, 1.0f);
    f1 = (1.0f - h) * (1.0f + h);
}

// Pre-cast W1..W3 to f16, repacked as BK=16 slabs TRANSPOSED [kg][n][8f16]:
// slab = l*16 + (k>>4) (8KB each); byte = ((k>>3)&1)*4096 + n*16 + (k&7)*2.
// B-frag reads (consecutive n, 16B stride) are bank-conflict-free by construction.
// d_ws: 48 slabs x 8KB = 384KB.
__global__ void prep_w(const float* __restrict__ W1, const float* __restrict__ W2,
                       const float* __restrict__ W3, char* __restrict__ ws)
{
    int idx = blockIdx.x * 256 + threadIdx.x;     // 3*65536 elements
    int l = idx >> 16;
    int e = idx & 65535;
    int k = e >> 8, n = e & 255;
    const float* W = (l == 0) ? W1 : (l == 1) ? W2 : W3;
    float w = W[e];
    int slab = l * 16 + (k >> 4);
    int byte_in = ((k >> 3) & 1) * 4096 + n * 16 + (k & 7) * 2;
    *(_Float16*)(ws + (size_t)slab * 8192 + byte_in) = (_Float16)w;
}

// Fused PINN forward + Taylor streams; 32x32x16 f16 MFMA, fp32 accum.
// GEMM row = S*p + s2 (point-interleaved). 8 waves = 2 row-groups x 4 col-groups,
// each wave 2x2 tiles of 32x32. 16 BK=16 phases/layer; per phase:
// { vmcnt(0)[prev pf done, issued a phase ago] ; s_barrier ; issue pf(g+1) ;
//   2 A + 2 B ds_read_b128 ; 4 MFMA }. Cross-block overlap hides the rest.
template<int S, int PTS>
__global__ void __launch_bounds__(512, 4)
pinn_mfma(const float* __restrict__ W0, const float* __restrict__ b0,
          const float* __restrict__ b1, const float* __restrict__ b2,
          const float* __restrict__ b3,
          const float* __restrict__ W4, const float* __restrict__ b4,
          const char* __restrict__ wpre,
          const float* __restrict__ tx, float* __restrict__ out)
{
    extern __shared__ char lds[];
    const int tid  = threadIdx.x;
    const int lane = tid & 63;
    const int wid  = tid >> 6;
    const int wr   = wid & 1;          // row-group: row-tiles {2wr, 2wr+1}
    const int wc   = wid >> 1;         // col-group: col-tiles {2wc, 2wc+1}
    const int pbase = blockIdx.x * PTS;
    constexpr int CG = 512 / PTS;      // threads per point (layer 0)
    constexpr int NC = 256 / CG;       // cols per thread (layer 0)
    const int ep  = tid / CG;
    const int ec0 = (tid % CG) * NC;

    // issue prefetch of slab 0 (8KB = 512 threads x 16B); hides under layer 0
    __builtin_amdgcn_global_load_lds((gu32*)(wpre + tid * 16),
                                     (lu32*)(lds + LDS_W + tid * 16), 16, 0, 0);

    // ---------------- layer 0: 2 -> 256 (elementwise into LDS act) ----------------
    {
        const float tt = tx[2 * (pbase + ep) + 0];
        const float xx = tx[2 * (pbase + ep) + 1];
        for (int cb = ec0; cb < ec0 + NC; cb += 8) {
            alignas(16) float w0r[8], w1r[8], bb[8];
            *(f32x4*)&w0r[0] = *(const f32x4*)(W0 + cb);
            *(f32x4*)&w0r[4] = *(const f32x4*)(W0 + cb + 4);
            *(f32x4*)&w1r[0] = *(const f32x4*)(W0 + HID + cb);
            *(f32x4*)&w1r[4] = *(const f32x4*)(W0 + HID + cb + 4);
            *(f32x4*)&bb[0]  = *(const f32x4*)(b0 + cb);
            *(f32x4*)&bb[4]  = *(const f32x4*)(b0 + cb + 4);
            f16x8 vhi[S];
            #pragma unroll
            for (int j = 0; j < 8; ++j) {
                float z = fmaf(tt, w0r[j], fmaf(xx, w1r[j], bb[j]));
                float h, f1;
                tanh_f1(z, h, f1);
                vhi[0][j] = (_Float16)h;
                if (S == 2) {
                    vhi[1][j] = (_Float16)(f1 * w0r[j]);
                } else if (S == 4) {
                    float d1 = w0r[j] + w1r[j];
                    float d2 = w0r[j] - w1r[j];
                    float f2 = -2.0f * h * f1;
                    vhi[1][j] = (_Float16)(f1 * d1);
                    vhi[2][j] = (_Float16)(f1 * d2);
                    vhi[3][j] = (_Float16)(f2 * d1 * d2);
                }
            }
            #pragma unroll
            for (int s2 = 0; s2 < S; ++s2) {
                int row = ep * S + s2;      // point-interleaved
                *(f16x8*)(lds + LDS_HI + act_off(row, cb * 2)) = vhi[s2];
            }
        }
    }

    // bias preload: one col per lane per col-tile
    const int c0 = (wc * 2) * 32 + (lane & 31);
    float bcv[3][2];
    bcv[0][0] = b1[c0]; bcv[0][1] = b1[c0 + 32];
    bcv[1][0] = b2[c0]; bcv[1][1] = b2[c0 + 32];
    bcv[2][0] = b3[c0]; bcv[2][1] = b3[c0 + 32];

    // act writes visible + slab 0 landed, block-wide
    asm volatile("s_waitcnt vmcnt(0) lgkmcnt(0)" ::: "memory");
    __builtin_amdgcn_sched_barrier(0);
    __builtin_amdgcn_s_barrier();
    __builtin_amdgcn_sched_barrier(0);

    // ---------------- layers 1..3: 256 -> 256 ----------------
    #pragma unroll
    for (int l = 0; l < 3; ++l) {
        f32x16 acc[2][2];
        #pragma unroll
        for (int i = 0; i < 2; ++i)
            #pragma unroll
            for (int j = 0; j < 2; ++j)
                acc[i][j] = (f32x16){0.f,0.f,0.f,0.f,0.f,0.f,0.f,0.f,
                                     0.f,0.f,0.f,0.f,0.f,0.f,0.f,0.f};

        #pragma unroll
        for (int ph = 0; ph < 16; ++ph) {
            const int g = l * 16 + ph;
            if (ph > 0) {
                // pf(g) was issued one phase ago -> wait is ~free; barrier makes
                // it block-wide AND retires all readers of buf[(g-1)&1].
                asm volatile("s_waitcnt vmcnt(0)" ::: "memory");
                __builtin_amdgcn_s_barrier();
                __builtin_amdgcn_sched_barrier(0);
            }
            if (g < 47) {    // issue prefetch of next slab into other buffer
                __builtin_amdgcn_global_load_lds(
                    (gu32*)(wpre + (size_t)(g + 1) * 8192 + tid * 16),
                    (lu32*)(lds + LDS_W + ((g + 1) & 1) * 8192 + tid * 16), 16, 0, 0);
            }
            const int kbyte = ph * 32 + ((lane >> 5) << 4);
            f16x8 av[2], bv[2];
            #pragma unroll
            for (int i = 0; i < 2; ++i) {
                const int row = (wr * 2 + i) * 32 + (lane & 31);
                av[i] = *(const f16x8*)(lds + LDS_HI + act_off(row, kbyte));
            }
            const char* wb = lds + LDS_W + (g & 1) * 8192 + ((lane >> 5) << 12);
            #pragma unroll
            for (int j = 0; j < 2; ++j) {
                const int n = (wc * 2 + j) * 32 + (lane & 31);
                bv[j] = *(const f16x8*)(wb + n * 16);
            }
            __builtin_amdgcn_s_setprio(1);
            acc[0][0] = __builtin_amdgcn_mfma_f32_32x32x16_f16(av[0], bv[0], acc[0][0], 0, 0, 0);
            acc[0][1] = __builtin_amdgcn_mfma_f32_32x32x16_f16(av[0], bv[1], acc[0][1], 0, 0, 0);
            acc[1][0] = __builtin_amdgcn_mfma_f32_32x32x16_f16(av[1], bv[0], acc[1][0], 0, 0, 0);
            acc[1][1] = __builtin_amdgcn_mfma_f32_32x32x16_f16(av[1], bv[1], acc[1][1], 0, 0, 0);
            __builtin_amdgcn_s_setprio(0);
        }
        __builtin_amdgcn_s_barrier();   // all act/W reads of this layer done

        // ---- in-register epilogue (overlaps the in-flight next-layer prefetch) ----
        // C/D: col = ctile*32 + (lane&31); row-in-tile = (reg&3)+8*(reg>>2)+4*(lane>>5)
        #pragma unroll
        for (int i = 0; i < 2; ++i) {
            #pragma unroll
            for (int j = 0; j < 2; ++j) {
                const int colj = (wc * 2 + j) * 32 + (lane & 31);
                const float bias = bcv[l][j];
                const int rtb = (wr * 2 + i) * 32 + 4 * (lane >> 5);
                #pragma unroll
                for (int q = 0; q < 4; ++q) {
                    const int rb = rtb + 8 * q;
                    if (S == 4) {
                        float z0 = acc[i][j][4*q+0] + bias;
                        float z1 = acc[i][j][4*q+1];
                        float z2 = acc[i][j][4*q+2];
                        float zm = acc[i][j][4*q+3];
                        float h, f1;
                        tanh_f1(z0, h, f1);
                        float f2 = -2.0f * h * f1;
                        *(_Float16*)(lds + LDS_HI + act_off(rb+0, colj*2)) = (_Float16)h;
                        *(_Float16*)(lds + LDS_HI + act_off(rb+1, colj*2)) = (_Float16)(f1 * z1);
                        *(_Float16*)(lds + LDS_HI + act_off(rb+2, colj*2)) = (_Float16)(f1 * z2);
                        *(_Float16*)(lds + LDS_HI + act_off(rb+3, colj*2)) =
                            (_Float16)(fmaf(f1, zm, f2 * z1 * z2));
                    } else if (S == 2) {
                        #pragma unroll
                        for (int pp = 0; pp < 2; ++pp) {
                            float z0 = acc[i][j][4*q+2*pp+0] + bias;
                            float zd = acc[i][j][4*q+2*pp+1];
                            float h, f1;
                            tanh_f1(z0, h, f1);
                            *(_Float16*)(lds + LDS_HI + act_off(rb+2*pp+0, colj*2)) = (_Float16)h;
                            *(_Float16*)(lds + LDS_HI + act_off(rb+2*pp+1, colj*2)) = (_Float16)(f1 * zd);
                        }
                    } else {
                        #pragma unroll
                        for (int m = 0; m < 4; ++m) {
                            float z0 = acc[i][j][4*q+m] + bias;
                            float h, f1;
                            tanh_f1(z0, h, f1);
                            *(_Float16*)(lds + LDS_HI + act_off(rb+m, colj*2)) = (_Float16)h;
                        }
                    }
                }
            }
        }
        // act visible + any in-flight prefetch drained, block-wide
        asm volatile("s_waitcnt vmcnt(0) lgkmcnt(0)" ::: "memory");
        __builtin_amdgcn_sched_barrier(0);
        __builtin_amdgcn_s_barrier();
        __builtin_amdgcn_sched_barrier(0);
    }

    // ---------------- layer 4: 256 -> 1 ----------------
    if (S == 4) {
        // only the mixed stream (rows 4p+3) is needed
        const int p   = tid >> 4;     // 0..31
        const int seg = tid & 15;     // 16 lanes per point
        const int k0  = seg * 16;
        const int row = 4 * p + 3;
        float d = 0.0f;
        #pragma unroll
        for (int kb = 0; kb < 16; kb += 8) {
            f16x8 h8 = *(const f16x8*)(lds + LDS_HI + act_off(row, (k0 + kb) * 2));
            alignas(16) float wv[8];
            *(f32x4*)&wv[0] = *(const f32x4*)(W4 + k0 + kb);
            *(f32x4*)&wv[4] = *(const f32x4*)(W4 + k0 + kb + 4);
            #pragma unroll
            for (int j = 0; j < 8; ++j) d = fmaf((float)h8[j], wv[j], d);
        }
        #pragma unroll
        for (int off = 8; off > 0; off >>= 1) d += __shfl_down(d, off, 16);
        if (seg == 0) out[0 * N_PTS + pbase + p] = d;              // u_tt - u_xx
    } else {
        const int row = tid >> 2;     // 0..127
        const int seg = tid & 3;      // 4 lanes per row
        const int k0  = seg * 64;
        float d = 0.0f;
        #pragma unroll
        for (int kb = 0; kb < 64; kb += 8) {
            f16x8 h8 = *(const f16x8*)(lds + LDS_HI + act_off(row, (k0 + kb) * 2));
            alignas(16) float wv[8];
            *(f32x4*)&wv[0] = *(const f32x4*)(W4 + k0 + kb);
            *(f32x4*)&wv[4] = *(const f32x4*)(W4 + k0 + kb + 4);
            #pragma unroll
            for (int j = 0; j < 8; ++j) d = fmaf((float)h8[j], wv[j], d);
        }
        d += __shfl_down(d, 2, 4);
        d += __shfl_down(d, 1, 4);
        if (seg == 0) {
            if (S == 2) {
                const int p = row >> 1;
                if ((row & 1) == 0) out[1 * N_PTS + pbase + p] = d + b4[0];   // u_phi
                else                out[2 * N_PTS + pbase + p] = d;           // du/dt
            } else {
                out[3 * N_PTS + pbase + row] = d + b4[0];                     // u_bound
            }
        }
    }
}

extern "C" void kernel_launch(void* const* d_in, const int* in_sizes, int n_in,
                              void* d_out, int out_size, void* d_ws, size_t ws_size,
                              hipStream_t stream) {
    const float* W0 = (const float*)d_in[0];
    const float* b0 = (const float*)d_in[1];
    const float* W1 = (const float*)d_in[2];
    const float* b1 = (const float*)d_in[3];
    const float* W2 = (const float*)d_in[4];
    const float* b2 = (const float*)d_in[5];
    const float* W3 = (const float*)d_in[6];
    const float* b3 = (const float*)d_in[7];
    const float* W4 = (const float*)d_in[8];
    const float* b4 = (const float*)d_in[9];
    const float* tx_eq    = (const float*)d_in[10];
    const float* tx_init  = (const float*)d_in[11];
    const float* tx_bound = (const float*)d_in[12];
    float* out = (float*)d_out;
    char* wpre = (char*)d_ws;     // needs 384KB

    hipFuncSetAttribute((const void*)pinn_mfma<4,32>,  hipFuncAttributeMaxDynamicSharedMemorySize, LDS_SZ);
    hipFuncSetAttribute((const void*)pinn_mfma<2,64>,  hipFuncAttributeMaxDynamicSharedMemorySize, LDS_SZ);
    hipFuncSetAttribute((const void*)pinn_mfma<1,128>, hipFuncAttributeMaxDynamicSharedMemorySize, LDS_SZ);

    prep_w<<<768, 256, 0, stream>>>(W1, W2, W3, wpre);
    pinn_mfma<4,32> <<<N_PTS/32,  512, LDS_SZ, stream>>>(W0,b0,b1,b2,b3,W4,b4,wpre,tx_eq,   out);
    pinn_mfma<2,64> <<<N_PTS/64,  512, LDS_SZ, stream>>>(W0,b0,b1,b2,b3,W4,b4,wpre,tx_init, out);
    pinn_mfma<1,128><<<N_PTS/128, 512, LDS_SZ, stream>>>(W0,b0,b1,b2,b3,W4,b4,wpre,tx_bound,out);
}

// Round 10
// 563.663 us; speedup vs baseline: 1.2153x; 1.2153x over previous
//
#include <hip/hip_runtime.h>
#include <math.h>

#define N_PTS 131072
#define HID   256

typedef __attribute__((ext_vector_type(8)))  _Float16 f16x8;
typedef __attribute__((ext_vector_type(4)))  float    f32x4;
typedef __attribute__((ext_vector_type(16))) float    f32x16;
typedef unsigned int u32;
typedef __attribute__((address_space(1))) const u32 gu32;
typedef __attribute__((address_space(3))) u32       lu32;

// LDS map (48 KiB): act[64][256] f16 (32KB) | W double-buffer (2 x 8KB)
// 48KB/block + 256-thread blocks + <=170 regs -> 3 blocks/CU co-resident.
#define LDS_HI  0
#define LDS_W   32768
#define LDS_SZ  49152

// act plane: [row][k] f16, 16B-slot XOR on (row&7)
__device__ __forceinline__ int act_off(int row, int kbyte) {
    return row * 512 + (kbyte ^ ((row & 7) << 4));
}
// h = tanh(z), f1 = 1-h^2. Saturation-safe: s=inf -> h=1, f1=0.
__device__ __forceinline__ void tanh_f1(float z, float& h, float& f1) {
    float s = __expf(2.0f * z);
    float r = __builtin_amdgcn_rcpf(s + 1.0f);
    h  = fmaf(-2.0f, r, 1.0f);
    f1 = (1.0f - h) * (1.0f + h);
}

// Pre-cast W1..W3 to f16, repacked as BK=16 slabs TRANSPOSED [kg][n][8f16]:
// slab = l*16 + (k>>4) (8KB each); byte = ((k>>3)&1)*4096 + n*16 + (k&7)*2.
// B-frag reads (consecutive n, 16B stride) are bank-conflict-free.
// d_ws: 48 slabs x 8KB = 384KB.
__global__ void prep_w(const float* __restrict__ W1, const float* __restrict__ W2,
                       const float* __restrict__ W3, char* __restrict__ ws)
{
    int idx = blockIdx.x * 256 + threadIdx.x;     // 3*65536 elements
    int l = idx >> 16;
    int e = idx & 65535;
    int k = e >> 8, n = e & 255;
    const float* W = (l == 0) ? W1 : (l == 1) ? W2 : W3;
    float w = W[e];
    int slab = l * 16 + (k >> 4);
    int byte_in = ((k >> 3) & 1) * 4096 + n * 16 + (k & 7) * 2;
    *(_Float16*)(ws + (size_t)slab * 8192 + byte_in) = (_Float16)w;
}

// Stage one 8KB slab with 256 threads: two 16B loads, each covering a
// contiguous 4KB region so every load's LDS dst = wave-uniform base + lane*16
// (global_load_lds constraint, m104/m108 — R9's tid*32 pattern violated this).
__device__ __forceinline__ void stage_slab(const char* __restrict__ src,
                                           char* dst, int tid) {
    #pragma unroll
    for (int q = 0; q < 2; ++q) {
        __builtin_amdgcn_global_load_lds((gu32*)(src + q * 4096 + tid * 16),
                                         (lu32*)(dst + q * 4096 + tid * 16), 16, 0, 0);
    }
}

// Fused PINN forward + Taylor streams; 32x32x16 f16 MFMA, fp32 accum.
// GEMM row = S*p + s2 (point-interleaved), 64 rows/block. 4 waves; wave w owns
// col-tiles {2w,2w+1} and BOTH row-tiles (A re-read x4, B read x1).
// 16 BK=16 phases/layer: { vmcnt(0) ; s_barrier ; issue pf(g+1) ;
//   2 A + 2 B ds_read_b128 ; 4 MFMA }. 3 blocks/CU overlap the phases.
template<int S, int PTS>
__global__ void __launch_bounds__(256, 3)
pinn_mfma(const float* __restrict__ W0, const float* __restrict__ b0,
          const float* __restrict__ b1, const float* __restrict__ b2,
          const float* __restrict__ b3,
          const float* __restrict__ W4, const float* __restrict__ b4,
          const char* __restrict__ wpre,
          const float* __restrict__ tx, float* __restrict__ out)
{
    extern __shared__ char lds[];
    const int tid  = threadIdx.x;
    const int lane = tid & 63;
    const int wid  = tid >> 6;         // 0..3: col-tiles {2wid, 2wid+1}
    const int pbase = blockIdx.x * PTS;
    constexpr int CG = 256 / PTS;      // threads per point (layer 0)
    constexpr int NC = 256 / CG;       // cols per thread (layer 0)
    const int ep  = tid / CG;
    const int ec0 = (tid % CG) * NC;

    // issue prefetch of slab 0; hides under layer 0
    stage_slab(wpre, lds + LDS_W, tid);

    // ---------------- layer 0: 2 -> 256 (elementwise into LDS act) ----------------
    {
        const float tt = tx[2 * (pbase + ep) + 0];
        const float xx = tx[2 * (pbase + ep) + 1];
        for (int cb = ec0; cb < ec0 + NC; cb += 8) {
            alignas(16) float w0r[8], w1r[8], bb[8];
            *(f32x4*)&w0r[0] = *(const f32x4*)(W0 + cb);
            *(f32x4*)&w0r[4] = *(const f32x4*)(W0 + cb + 4);
            *(f32x4*)&w1r[0] = *(const f32x4*)(W0 + HID + cb);
            *(f32x4*)&w1r[4] = *(const f32x4*)(W0 + HID + cb + 4);
            *(f32x4*)&bb[0]  = *(const f32x4*)(b0 + cb);
            *(f32x4*)&bb[4]  = *(const f32x4*)(b0 + cb + 4);
            f16x8 vhi[S];
            #pragma unroll
            for (int j = 0; j < 8; ++j) {
                float z = fmaf(tt, w0r[j], fmaf(xx, w1r[j], bb[j]));
                float h, f1;
                tanh_f1(z, h, f1);
                vhi[0][j] = (_Float16)h;
                if (S == 2) {
                    vhi[1][j] = (_Float16)(f1 * w0r[j]);
                } else if (S == 4) {
                    float d1 = w0r[j] + w1r[j];
                    float d2 = w0r[j] - w1r[j];
                    float f2 = -2.0f * h * f1;
                    vhi[1][j] = (_Float16)(f1 * d1);
                    vhi[2][j] = (_Float16)(f1 * d2);
                    vhi[3][j] = (_Float16)(f2 * d1 * d2);
                }
            }
            #pragma unroll
            for (int s2 = 0; s2 < S; ++s2) {
                int row = ep * S + s2;      // point-interleaved
                *(f16x8*)(lds + LDS_HI + act_off(row, cb * 2)) = vhi[s2];
            }
        }
    }

    // bias preload: one col per lane per col-tile
    const int c0 = wid * 64 + (lane & 31);
    float bcv[3][2];
    bcv[0][0] = b1[c0]; bcv[0][1] = b1[c0 + 32];
    bcv[1][0] = b2[c0]; bcv[1][1] = b2[c0 + 32];
    bcv[2][0] = b3[c0]; bcv[2][1] = b3[c0 + 32];

    // act writes visible + slab 0 landed, block-wide
    asm volatile("s_waitcnt vmcnt(0) lgkmcnt(0)" ::: "memory");
    __builtin_amdgcn_sched_barrier(0);
    __builtin_amdgcn_s_barrier();
    __builtin_amdgcn_sched_barrier(0);

    // ---------------- layers 1..3: 256 -> 256 ----------------
    #pragma unroll
    for (int l = 0; l < 3; ++l) {
        f32x16 acc[2][2];
        #pragma unroll
        for (int i = 0; i < 2; ++i)
            #pragma unroll
            for (int j = 0; j < 2; ++j)
                acc[i][j] = (f32x16){0.f,0.f,0.f,0.f,0.f,0.f,0.f,0.f,
                                     0.f,0.f,0.f,0.f,0.f,0.f,0.f,0.f};

        #pragma unroll
        for (int ph = 0; ph < 16; ++ph) {
            const int g = l * 16 + ph;
            if (ph > 0) {
                // pf(g) issued one phase ago -> wait is short; barrier retires
                // all readers of buf[(g-1)&1] block-wide.
                asm volatile("s_waitcnt vmcnt(0)" ::: "memory");
                __builtin_amdgcn_s_barrier();
                __builtin_amdgcn_sched_barrier(0);
            }
            if (g < 47) {    // issue prefetch of next slab into other buffer
                stage_slab(wpre + (size_t)(g + 1) * 8192,
                           lds + LDS_W + ((g + 1) & 1) * 8192, tid);
            }
            const int kbyte = ph * 32 + ((lane >> 5) << 4);
            f16x8 av[2], bv[2];
            #pragma unroll
            for (int i = 0; i < 2; ++i) {
                const int row = i * 32 + (lane & 31);
                av[i] = *(const f16x8*)(lds + LDS_HI + act_off(row, kbyte));
            }
            const char* wb = lds + LDS_W + (g & 1) * 8192 + ((lane >> 5) << 12);
            #pragma unroll
            for (int j = 0; j < 2; ++j) {
                const int n = wid * 64 + j * 32 + (lane & 31);
                bv[j] = *(const f16x8*)(wb + n * 16);
            }
            __builtin_amdgcn_s_setprio(1);
            acc[0][0] = __builtin_amdgcn_mfma_f32_32x32x16_f16(av[0], bv[0], acc[0][0], 0, 0, 0);
            acc[0][1] = __builtin_amdgcn_mfma_f32_32x32x16_f16(av[0], bv[1], acc[0][1], 0, 0, 0);
            acc[1][0] = __builtin_amdgcn_mfma_f32_32x32x16_f16(av[1], bv[0], acc[1][0], 0, 0, 0);
            acc[1][1] = __builtin_amdgcn_mfma_f32_32x32x16_f16(av[1], bv[1], acc[1][1], 0, 0, 0);
            __builtin_amdgcn_s_setprio(0);
        }
        __builtin_amdgcn_s_barrier();   // all act/W reads of this layer done

        // ---- in-register epilogue (overlaps the in-flight next-layer prefetch) ----
        // C/D: col = ctile*32 + (lane&31); row-in-tile = (reg&3)+8*(reg>>2)+4*(lane>>5)
        #pragma unroll
        for (int i = 0; i < 2; ++i) {
            #pragma unroll
            for (int j = 0; j < 2; ++j) {
                const int colj = wid * 64 + j * 32 + (lane & 31);
                const float bias = bcv[l][j];
                const int rtb = i * 32 + 4 * (lane >> 5);
                #pragma unroll
                for (int q = 0; q < 4; ++q) {
                    const int rb = rtb + 8 * q;
                    if (S == 4) {
                        float z0 = acc[i][j][4*q+0] + bias;
                        float z1 = acc[i][j][4*q+1];
                        float z2 = acc[i][j][4*q+2];
                        float zm = acc[i][j][4*q+3];
                        float h, f1;
                        tanh_f1(z0, h, f1);
                        float f2 = -2.0f * h * f1;
                        *(_Float16*)(lds + LDS_HI + act_off(rb+0, colj*2)) = (_Float16)h;
                        *(_Float16*)(lds + LDS_HI + act_off(rb+1, colj*2)) = (_Float16)(f1 * z1);
                        *(_Float16*)(lds + LDS_HI + act_off(rb+2, colj*2)) = (_Float16)(f1 * z2);
                        *(_Float16*)(lds + LDS_HI + act_off(rb+3, colj*2)) =
                            (_Float16)(fmaf(f1, zm, f2 * z1 * z2));
                    } else if (S == 2) {
                        #pragma unroll
                        for (int pp = 0; pp < 2; ++pp) {
                            float z0 = acc[i][j][4*q+2*pp+0] + bias;
                            float zd = acc[i][j][4*q+2*pp+1];
                            float h, f1;
                            tanh_f1(z0, h, f1);
                            *(_Float16*)(lds + LDS_HI + act_off(rb+2*pp+0, colj*2)) = (_Float16)h;
                            *(_Float16*)(lds + LDS_HI + act_off(rb+2*pp+1, colj*2)) = (_Float16)(f1 * zd);
                        }
                    } else {
                        #pragma unroll
                        for (int m = 0; m < 4; ++m) {
                            float z0 = acc[i][j][4*q+m] + bias;
                            float h, f1;
                            tanh_f1(z0, h, f1);
                            *(_Float16*)(lds + LDS_HI + act_off(rb+m, colj*2)) = (_Float16)h;
                        }
                    }
                }
            }
        }
        // act visible + in-flight prefetch drained, block-wide
        asm volatile("s_waitcnt vmcnt(0) lgkmcnt(0)" ::: "memory");
        __builtin_amdgcn_sched_barrier(0);
        __builtin_amdgcn_s_barrier();
        __builtin_amdgcn_sched_barrier(0);
    }

    // ---------------- layer 4: 256 -> 1 ----------------
    if (S == 4) {
        // only the mixed stream (rows 4p+3) is needed
        const int p   = tid >> 4;     // 0..15
        const int seg = tid & 15;     // 16 lanes per point
        const int k0  = seg * 16;
        const int row = 4 * p + 3;
        float d = 0.0f;
        #pragma unroll
        for (int kb = 0; kb < 16; kb += 8) {
            f16x8 h8 = *(const f16x8*)(lds + LDS_HI + act_off(row, (k0 + kb) * 2));
            alignas(16) float wv[8];
            *(f32x4*)&wv[0] = *(const f32x4*)(W4 + k0 + kb);
            *(f32x4*)&wv[4] = *(const f32x4*)(W4 + k0 + kb + 4);
            #pragma unroll
            for (int j = 0; j < 8; ++j) d = fmaf((float)h8[j], wv[j], d);
        }
        #pragma unroll
        for (int off = 8; off > 0; off >>= 1) d += __shfl_down(d, off, 16);
        if (seg == 0) out[0 * N_PTS + pbase + p] = d;              // u_tt - u_xx
    } else {
        const int row = tid >> 2;     // 0..63
        const int seg = tid & 3;      // 4 lanes per row
        const int k0  = seg * 64;
        float d = 0.0f;
        #pragma unroll
        for (int kb = 0; kb < 64; kb += 8) {
            f16x8 h8 = *(const f16x8*)(lds + LDS_HI + act_off(row, (k0 + kb) * 2));
            alignas(16) float wv[8];
            *(f32x4*)&wv[0] = *(const f32x4*)(W4 + k0 + kb);
            *(f32x4*)&wv[4] = *(const f32x4*)(W4 + k0 + kb + 4);
            #pragma unroll
            for (int j = 0; j < 8; ++j) d = fmaf((float)h8[j], wv[j], d);
        }
        d += __shfl_down(d, 2, 4);
        d += __shfl_down(d, 1, 4);
        if (seg == 0) {
            if (S == 2) {
                const int p = row >> 1;
                if ((row & 1) == 0) out[1 * N_PTS + pbase + p] = d + b4[0];   // u_phi
                else                out[2 * N_PTS + pbase + p] = d;           // du/dt
            } else {
                out[3 * N_PTS + pbase + row] = d + b4[0];                     // u_bound
            }
        }
    }
}

extern "C" void kernel_launch(void* const* d_in, const int* in_sizes, int n_in,
                              void* d_out, int out_size, void* d_ws, size_t ws_size,
                              hipStream_t stream) {
    const float* W0 = (const float*)d_in[0];
    const float* b0 = (const float*)d_in[1];
    const float* W1 = (const float*)d_in[2];
    const float* b1 = (const float*)d_in[3];
    const float* W2 = (const float*)d_in[4];
    const float* b2 = (const float*)d_in[5];
    const float* W3 = (const float*)d_in[6];
    const float* b3 = (const float*)d_in[7];
    const float* W4 = (const float*)d_in[8];
    const float* b4 = (const float*)d_in[9];
    const float* tx_eq    = (const float*)d_in[10];
    const float* tx_init  = (const float*)d_in[11];
    const float* tx_bound = (const float*)d_in[12];
    float* out = (float*)d_out;
    char* wpre = (char*)d_ws;     // needs 384KB

    prep_w<<<768, 256, 0, stream>>>(W1, W2, W3, wpre);
    pinn_mfma<4,16><<<N_PTS/16, 256, LDS_SZ, stream>>>(W0,b0,b1,b2,b3,W4,b4,wpre,tx_eq,   out);
    pinn_mfma<2,32><<<N_PTS/32, 256, LDS_SZ, stream>>>(W0,b0,b1,b2,b3,W4,b4,wpre,tx_init, out);
    pinn_mfma<1,64><<<N_PTS/64, 256, LDS_SZ, stream>>>(W0,b0,b1,b2,b3,W4,b4,wpre,tx_bound,out);
}